// Round 5
// baseline (3087.882 us; speedup 1.0000x reference)
//
#include <hip/hip_runtime.h>
#include <stdint.h>

#define T_TOK 8192
#define DDIM 1024
#define NEXP 8
#define HDIM 3072

typedef __attribute__((ext_vector_type(8))) short bfrag;   // 8 bf16 (4 VGPRs)
typedef __attribute__((ext_vector_type(4))) float facc;    // 4 fp32 acc

__device__ __forceinline__ unsigned short f2bf(float f) {
  unsigned int u = __float_as_uint(f);
  u += 0x7FFFu + ((u >> 16) & 1u);      // RNE
  return (unsigned short)(u >> 16);
}

__device__ __forceinline__ int imin(int a, int b) { return a < b ? a : b; }

// ---------------- gating: one wave per token (byte-identical to passing R1) ----------------
__global__ __launch_bounds__(64) void gate_topk(
    const float* __restrict__ x, const float* __restrict__ gw,
    int* __restrict__ counts, int* __restrict__ tok_list,
    float* __restrict__ wt_list)
{
  const int t = blockIdx.x;
  const int lane = threadIdx.x;
  const float* xr = x + (size_t)t * DDIM;
  float p[NEXP];
#pragma unroll
  for (int e = 0; e < NEXP; ++e) p[e] = 0.f;
#pragma unroll 4
  for (int i = 0; i < DDIM / 64; ++i) {
    const int d = i * 64 + lane;
    const float xv = xr[d];
    const float4 g0 = *(const float4*)(gw + (size_t)d * NEXP);
    const float4 g1 = *(const float4*)(gw + (size_t)d * NEXP + 4);
    p[0] += xv * g0.x; p[1] += xv * g0.y; p[2] += xv * g0.z; p[3] += xv * g0.w;
    p[4] += xv * g1.x; p[5] += xv * g1.y; p[6] += xv * g1.z; p[7] += xv * g1.w;
  }
#pragma unroll
  for (int off = 32; off > 0; off >>= 1) {
#pragma unroll
    for (int e = 0; e < NEXP; ++e) p[e] += __shfl_down(p[e], off);
  }
  if (lane == 0) {
    int i1 = 0; float v1 = p[0];
#pragma unroll
    for (int e = 1; e < NEXP; ++e) if (p[e] > v1) { v1 = p[e]; i1 = e; }
    int i2 = -1; float v2 = -3.4e38f;
#pragma unroll
    for (int e = 0; e < NEXP; ++e) if (e != i1 && p[e] > v2) { v2 = p[e]; i2 = e; }
    const float w0 = 1.f / (1.f + __expf(v2 - v1));   // sigmoid(l1-l2)
    int q1 = atomicAdd(&counts[i1 * 32], 1);
    tok_list[i1 * T_TOK + q1] = t;
    wt_list[i1 * T_TOK + q1] = w0;
    int q2 = atomicAdd(&counts[i2 * 32], 1);
    tok_list[i2 * T_TOK + q2] = t;
    wt_list[i2 * T_TOK + q2] = 1.f - w0;
  }
}

// ---------------- GEMM1: h = silu(Xg@w1) * (Xg@w3) ----------------
// 128x128 tile, BK=32, 4 waves as 2x2, each wave 4x4 of 16x16x32 MFMA per matrix.
// R1 primitives only: float4 global loads, in-loop f2bf, [..][40]-padded LDS,
// aligned b128 frag reads, scalar bf16 epilogue stores.
__global__ __launch_bounds__(256) void moe_gemm1(
    const float* __restrict__ x, const float* __restrict__ w1,
    const float* __restrict__ w3, const int* __restrict__ counts,
    const int* __restrict__ tok_list, unsigned short* __restrict__ h_buf, int e)
{
  const int cnt = counts[e * 32];
  const int p0 = blockIdx.y * 128;
  if (p0 >= cnt) return;                 // live blocks => cnt >= 1
  const int n0 = blockIdx.x * 128;

  __shared__ unsigned short As[128][40];     // [row][k]; 80B pitch => b128-aligned frag reads
  __shared__ unsigned short B1s[128][40];    // [n][k]
  __shared__ unsigned short B3s[128][40];

  const int tid = threadIdx.x;
  const int lane = tid & 63;
  const int wv = tid >> 6;
  const float* w1e = w1 + (size_t)e * DDIM * HDIM;
  const float* w3e = w3 + (size_t)e * DDIM * HDIM;
  const int* tl = tok_list + e * T_TOK;

  // A staging: thread -> (row = tid>>1, 16-wide k-seg (tid&1)*16); clamped gather
  const int arow = tid >> 1;
  const int akseg = (tid & 1) * 16;
  const int tok = tl[imin(p0 + arow, cnt - 1)];
  const float* gA = x + (size_t)tok * DDIM + akseg;

  // B staging: thread -> 4 n x 4 k block: n=(tid&31)*4, k=(tid>>5)*4
  const int bn = (tid & 31) * 4;
  const int bk4 = (tid >> 5) * 4;
  const float* gB1 = w1e + (size_t)bk4 * HDIM + n0 + bn;
  const float* gB3 = w3e + (size_t)bk4 * HDIM + n0 + bn;

  facc acc1[4][4], acc3[4][4];
#pragma unroll
  for (int i = 0; i < 4; ++i)
#pragma unroll
    for (int j = 0; j < 4; ++j)
#pragma unroll
      for (int r = 0; r < 4; ++r) { acc1[i][j][r] = 0.f; acc3[i][j][r] = 0.f; }

  const int wm = (wv & 1) * 64, wn = (wv >> 1) * 64;
  const int lrow = lane & 15, kq = (lane >> 4) * 8;

  for (int k0 = 0; k0 < DDIM; k0 += 32) {
    { // A: 16 floats -> 16 bf16 -> 2 x uint4
      const float4 f0 = *(const float4*)(gA + k0);
      const float4 f1 = *(const float4*)(gA + k0 + 4);
      const float4 f2 = *(const float4*)(gA + k0 + 8);
      const float4 f3 = *(const float4*)(gA + k0 + 12);
      union { unsigned short s[16]; uint4 v[2]; } t;
      t.s[0]=f2bf(f0.x);  t.s[1]=f2bf(f0.y);  t.s[2]=f2bf(f0.z);  t.s[3]=f2bf(f0.w);
      t.s[4]=f2bf(f1.x);  t.s[5]=f2bf(f1.y);  t.s[6]=f2bf(f1.z);  t.s[7]=f2bf(f1.w);
      t.s[8]=f2bf(f2.x);  t.s[9]=f2bf(f2.y);  t.s[10]=f2bf(f2.z); t.s[11]=f2bf(f2.w);
      t.s[12]=f2bf(f3.x); t.s[13]=f2bf(f3.y); t.s[14]=f2bf(f3.z); t.s[15]=f2bf(f3.w);
      *(uint4*)&As[arow][akseg]     = t.v[0];
      *(uint4*)&As[arow][akseg + 8] = t.v[1];
    }
    { // B1/B3: 4 k-rows x 4 n each; transposed scalar writes (R1 pattern)
#pragma unroll
      for (int j = 0; j < 4; ++j) {
        const float4 f1v = *(const float4*)(gB1 + (size_t)(k0 + j) * HDIM);
        B1s[bn + 0][bk4 + j] = f2bf(f1v.x);
        B1s[bn + 1][bk4 + j] = f2bf(f1v.y);
        B1s[bn + 2][bk4 + j] = f2bf(f1v.z);
        B1s[bn + 3][bk4 + j] = f2bf(f1v.w);
        const float4 f3v = *(const float4*)(gB3 + (size_t)(k0 + j) * HDIM);
        B3s[bn + 0][bk4 + j] = f2bf(f3v.x);
        B3s[bn + 1][bk4 + j] = f2bf(f3v.y);
        B3s[bn + 2][bk4 + j] = f2bf(f3v.z);
        B3s[bn + 3][bk4 + j] = f2bf(f3v.w);
      }
    }
    __syncthreads();
    bfrag a[4];
#pragma unroll
    for (int mt = 0; mt < 4; ++mt) a[mt] = *(const bfrag*)&As[wm + mt * 16 + lrow][kq];
#pragma unroll
    for (int nt = 0; nt < 4; ++nt) {
      const bfrag b1 = *(const bfrag*)&B1s[wn + nt * 16 + lrow][kq];
      const bfrag b3 = *(const bfrag*)&B3s[wn + nt * 16 + lrow][kq];
#pragma unroll
      for (int mt = 0; mt < 4; ++mt) {
        acc1[mt][nt] = __builtin_amdgcn_mfma_f32_16x16x32_bf16(a[mt], b1, acc1[mt][nt], 0, 0, 0);
        acc3[mt][nt] = __builtin_amdgcn_mfma_f32_16x16x32_bf16(a[mt], b3, acc3[mt][nt], 0, 0, 0);
      }
    }
    __syncthreads();
  }

  // epilogue: h = silu(g)*u -> bf16 (verified C/D map: col=lane&15, row=(lane>>4)*4+r)
  const int colb = lane & 15, rq = (lane >> 4) * 4;
#pragma unroll
  for (int mt = 0; mt < 4; ++mt) {
#pragma unroll
    for (int r = 0; r < 4; ++r) {
      const int p = p0 + wm + mt * 16 + rq + r;
      if (p < cnt) {
        unsigned short* dst = h_buf + (size_t)p * HDIM + n0 + wn + colb;
#pragma unroll
        for (int nt = 0; nt < 4; ++nt) {
          const float g = acc1[mt][nt][r];
          const float u = acc3[mt][nt][r];
          dst[nt * 16] = f2bf(g * u / (1.f + __expf(-g)));
        }
      }
    }
  }
}

// ---------------- GEMM2: out[tok] += wt * (h @ w2), 128x128 tile ----------------
__global__ __launch_bounds__(256) void moe_gemm2(
    const unsigned short* __restrict__ h_buf, const float* __restrict__ w2,
    const int* __restrict__ counts, const int* __restrict__ tok_list,
    const float* __restrict__ wt_list, float* __restrict__ out, int e)
{
  const int cnt = counts[e * 32];
  const int p0 = blockIdx.y * 128;
  if (p0 >= cnt) return;
  const int n0 = blockIdx.x * 128;

  __shared__ unsigned short As[128][40];
  __shared__ unsigned short Bs[128][40];

  const int tid = threadIdx.x;
  const int lane = tid & 63;
  const int wv = tid >> 6;
  const float* w2e = w2 + (size_t)e * HDIM * DDIM;
  const int* tl = tok_list + e * T_TOK;
  const float* wl = wt_list + e * T_TOK;

  const int arow = tid >> 1;
  const int akseg = (tid & 1) * 16;
  const int prow = imin(p0 + arow, cnt - 1);
  const unsigned short* gA = h_buf + (size_t)prow * HDIM + akseg;   // bf16 source (R1 pattern)

  const int bn = (tid & 31) * 4;
  const int bk4 = (tid >> 5) * 4;
  const float* gB = w2e + (size_t)bk4 * DDIM + n0 + bn;

  facc acc[4][4];
#pragma unroll
  for (int i = 0; i < 4; ++i)
#pragma unroll
    for (int j = 0; j < 4; ++j)
#pragma unroll
      for (int r = 0; r < 4; ++r) acc[i][j][r] = 0.f;

  const int wm = (wv & 1) * 64, wn = (wv >> 1) * 64;
  const int lrow = lane & 15, kq = (lane >> 4) * 8;

  for (int k0 = 0; k0 < HDIM; k0 += 32) {
    *(uint4*)&As[arow][akseg]     = *(const uint4*)(gA + k0);
    *(uint4*)&As[arow][akseg + 8] = *(const uint4*)(gA + k0 + 8);
#pragma unroll
    for (int j = 0; j < 4; ++j) {
      const float4 f = *(const float4*)(gB + (size_t)(k0 + j) * DDIM);
      Bs[bn + 0][bk4 + j] = f2bf(f.x);
      Bs[bn + 1][bk4 + j] = f2bf(f.y);
      Bs[bn + 2][bk4 + j] = f2bf(f.z);
      Bs[bn + 3][bk4 + j] = f2bf(f.w);
    }
    __syncthreads();
    bfrag a[4];
#pragma unroll
    for (int mt = 0; mt < 4; ++mt) a[mt] = *(const bfrag*)&As[wm + mt * 16 + lrow][kq];
#pragma unroll
    for (int nt = 0; nt < 4; ++nt) {
      const bfrag b = *(const bfrag*)&Bs[wn + nt * 16 + lrow][kq];
#pragma unroll
      for (int mt = 0; mt < 4; ++mt)
        acc[mt][nt] = __builtin_amdgcn_mfma_f32_16x16x32_bf16(a[mt], b, acc[mt][nt], 0, 0, 0);
    }
    __syncthreads();
  }

  const int colb = lane & 15, rq = (lane >> 4) * 4;
#pragma unroll
  for (int mt = 0; mt < 4; ++mt) {
#pragma unroll
    for (int r = 0; r < 4; ++r) {
      const int p = p0 + wm + mt * 16 + rq + r;
      if (p < cnt) {
        const int tok = tl[p];
        const float wt = wl[p];
        float* dst = out + (size_t)tok * DDIM + n0 + wn + colb;
#pragma unroll
        for (int nt = 0; nt < 4; ++nt)
          atomicAdd(dst + nt * 16, acc[mt][nt][r] * wt);
      }
    }
  }
}

__global__ void ws_too_small(float* out, int n) {
  int i = blockIdx.x * 256 + threadIdx.x;
  if (i < n) out[i] = 1.0e6f;   // sentinel: workspace shortage, not a math bug
}

extern "C" void kernel_launch(void* const* d_in, const int* in_sizes, int n_in,
                              void* d_out, int out_size, void* d_ws, size_t ws_size,
                              hipStream_t stream) {
  // setup_inputs dict order: x, gate_w, w1, w3, w2
  const float* x  = (const float*)d_in[0];
  const float* gw = (const float*)d_in[1];
  const float* w1 = (const float*)d_in[2];
  const float* w3 = (const float*)d_in[3];
  const float* w2 = (const float*)d_in[4];
  float* out = (float*)d_out;

  // R1-proven workspace layout (no converters): counts | tok_list | wt_list | h_buf
  const size_t off_tok = 1024;
  const size_t off_wt  = off_tok + (size_t)NEXP * T_TOK * 4;
  const size_t off_h   = off_wt + (size_t)NEXP * T_TOK * 4;
  const size_t need    = off_h + (size_t)T_TOK * HDIM * 2;     // ~50.9 MB
  if (ws_size < need) {
    ws_too_small<<<(out_size + 255) / 256, 256, 0, stream>>>(out, out_size);
    return;
  }
  int* counts = (int*)d_ws;
  int* tok_list = (int*)((char*)d_ws + off_tok);
  float* wt_list = (float*)((char*)d_ws + off_wt);
  unsigned short* h_buf = (unsigned short*)((char*)d_ws + off_h);

  hipMemsetAsync(counts, 0, 1024, stream);
  hipMemsetAsync(out, 0, (size_t)out_size * sizeof(float), stream);

  gate_topk<<<T_TOK, 64, 0, stream>>>(x, gw, counts, tok_list, wt_list);
  for (int e = 0; e < NEXP; ++e) {
    moe_gemm1<<<dim3(HDIM / 128, T_TOK / 128), 256, 0, stream>>>(
        x, w1, w3, counts, tok_list, h_buf, e);
    moe_gemm2<<<dim3(DDIM / 128, T_TOK / 128), 256, 0, stream>>>(
        h_buf, w2, counts, tok_list, wt_list, out, e);
  }
}